// Round 4
// baseline (284.378 us; speedup 1.0000x reference)
//
#include <hip/hip_runtime.h>
#include <hip/hip_bf16.h>

// SwitchLinear: B=4,S=2048,D_IN=1024,D_OUT=1024,E=8
// Established contract: ALL inputs fp32, OUTPUT fp32 (out_size=8388609 floats:
// 8192x1024 dense out + aux scalar). ws >= 262400 B. Routing = argmax of fp32
// gate logits; out[t,:] = x[t]@We[top1]^T + be[top1]; aux = mean((mean_gate*E)^2).
// Value GEMM: bf16 MFMA (input-rounding error ~1e-3 << 6.4e-2 threshold).
//
// v5: LDS-FREE gemm. v3's 81us was structural serialization (2 blk/CU, serial
// load->cvt->LDS->barrier->dsread->MFMA chain, ~2.5us/K-step, no pipe >31%).
// v4's 1-D decode regressed (n-siblings 512 slots apart -> L2 thrash).
// Now: 1 wave per block, 64x64 output tile, fragments loaded DIRECTLY from
// global (per-lane gather for A tokens), cvt in reg, 2-stage register double
// buffer, zero barriers/LDS. 4096 blocks; decode keeps the 16 n-siblings of
// each (m,e) consecutive AND on one XCD (d%8 = m&7).
// v3 (kept): zero-atomic routing via per-block records + 1-block scan kernel.

#define NTOK 8192
#define DIN  1024
#define DOUT 1024
#define NE   8

typedef unsigned short u16;
typedef unsigned int   u32;
typedef unsigned long long u64;
typedef short  bf16x8 __attribute__((ext_vector_type(8)));
typedef float  f32x4  __attribute__((ext_vector_type(4)));

__device__ __forceinline__ u16 f2bf(float f) {
    __hip_bfloat16 h = __float2bfloat16(f);   // RNE
    return *(u16*)&h;
}

// ws layout: [0,32) counts[8] | [256, 262400) tok_list[8][8192]
// First 32KB of tok_list region doubles as gate-record staging (512 x 64B).

// ---------------------------------------------------------------------------
// gate: 512 blocks x 256 thr; each block 16 tokens, each wave 4 tokens.
// Per token: 8 lane-groups x 8 lanes; group g computes expert g. No atomics.
// ---------------------------------------------------------------------------
__global__ __launch_bounds__(256) void gate_kernel(
    const float* __restrict__ x, const float* __restrict__ Wg,
    const float* __restrict__ bg, u32* __restrict__ stage)
{
    __shared__ int   am_s[16];
    __shared__ float mg_s[4][NE];

    const int tid  = threadIdx.x;
    const int wave = tid >> 6;
    const int lane = tid & 63;
    const int g    = lane >> 3;
    const int sub  = lane & 7;

    const float* wr = Wg + g * DIN + 4 * sub;

    float bgl[NE];
    #pragma unroll
    for (int e = 0; e < NE; ++e) bgl[e] = bg[e];

    float mgacc = 0.f;

    #pragma unroll 1
    for (int it = 0; it < 4; ++it) {
        const int t = blockIdx.x * 16 + wave * 4 + it;
        const float* xr = x + (size_t)t * DIN + 4 * sub;

        float acc0 = 0.f, acc1 = 0.f, acc2 = 0.f, acc3 = 0.f;
        #pragma unroll
        for (int j = 0; j < 8; ++j) {
            const int k = j * 128;
            f32x4 x0 = *(const f32x4*)(xr + k);
            f32x4 w0 = *(const f32x4*)(wr + k);
            f32x4 x1 = *(const f32x4*)(xr + k + 32);
            f32x4 w1 = *(const f32x4*)(wr + k + 32);
            f32x4 x2 = *(const f32x4*)(xr + k + 64);
            f32x4 w2 = *(const f32x4*)(wr + k + 64);
            f32x4 x3 = *(const f32x4*)(xr + k + 96);
            f32x4 w3 = *(const f32x4*)(wr + k + 96);
            #pragma unroll
            for (int q = 0; q < 4; ++q) {
                acc0 = fmaf(w0[q], x0[q], acc0);
                acc1 = fmaf(w1[q], x1[q], acc1);
                acc2 = fmaf(w2[q], x2[q], acc2);
                acc3 = fmaf(w3[q], x3[q], acc3);
            }
        }
        float acc = (acc0 + acc1) + (acc2 + acc3);

        acc += __shfl_xor(acc, 1, 64);
        acc += __shfl_xor(acc, 2, 64);
        acc += __shfl_xor(acc, 4, 64);

        float logit[NE];
        #pragma unroll
        for (int e = 0; e < NE; ++e)
            logit[e] = __shfl(acc, e * 8, 64) + bgl[e];

        float m = logit[0]; int am = 0;
        #pragma unroll
        for (int e = 1; e < NE; ++e) if (logit[e] > m) { m = logit[e]; am = e; }

        float p[NE], s = 0.f;
        #pragma unroll
        for (int e = 0; e < NE; ++e) { p[e] = __expf(logit[e] - m); s += p[e]; }
        const float inv = 1.f / s;

        float psel = p[0];
        #pragma unroll
        for (int e = 1; e < NE; ++e) psel = (lane == e) ? p[e] : psel;
        if (lane < NE) mgacc += psel * inv;

        if (lane == 0) am_s[wave * 4 + it] = am;
    }

    if (lane < NE) mg_s[wave][lane] = mgacc;
    __syncthreads();

    u32* rec = stage + (size_t)blockIdx.x * 16;
    if (tid == 0) {
        u64 pack = 0;
        #pragma unroll
        for (int i = 0; i < 16; ++i) pack |= (u64)am_s[i] << (4 * i);
        *(u64*)rec = pack;
    }
    if (tid < NE) {
        float s = mg_s[0][tid] + mg_s[1][tid] + mg_s[2][tid] + mg_s[3][tid];
        rec[2 + tid] = __float_as_uint(s);
    }
}

// ---------------------------------------------------------------------------
// route: 1 block x 512 threads. Thread i owns gate-block i (16 tokens).
// Count -> per-expert exclusive scan over blocks -> scatter -> counts/aux.
// ---------------------------------------------------------------------------
__global__ __launch_bounds__(512) void route_kernel(
    const u32* __restrict__ stage, int* __restrict__ counts,
    int* __restrict__ tok_list, float* __restrict__ out)
{
    __shared__ float mgl[512][NE];
    __shared__ int   c[512][9];
    __shared__ float tot_s[NE];

    const int tid  = threadIdx.x;
    const int wave = tid >> 6;
    const int lane = tid & 63;

    const u64 pack = *(const u64*)(stage + (size_t)tid * 16);
    #pragma unroll
    for (int e = 0; e < NE; ++e)
        mgl[tid][e] = __uint_as_float(stage[tid * 16 + 2 + e]);

    #pragma unroll
    for (int e = 0; e < 9; ++e) c[tid][e] = 0;

    #pragma unroll
    for (int it = 0; it < 16; ++it) {
        int e3 = (int)((pack >> (4 * it)) & 7);
        c[tid][e3]++;
    }
    __syncthreads();

    {
        const int e = wave;
        int carry = 0;
        #pragma unroll 1
        for (int ch = 0; ch < 8; ++ch) {
            int v = c[ch * 64 + lane][e];
            int incl = v;
            #pragma unroll
            for (int off = 1; off < 64; off <<= 1) {
                int n = __shfl_up(incl, off, 64);
                if (lane >= off) incl += n;
            }
            c[ch * 64 + lane][e] = incl - v + carry;
            carry += __shfl(incl, 63, 64);
        }
        if (lane == 0) counts[e] = carry;
    }
    __syncthreads();

    #pragma unroll
    for (int it = 0; it < 16; ++it) {
        int e3 = (int)((pack >> (4 * it)) & 7);
        int pos = c[tid][e3]++;
        tok_list[e3 * NTOK + pos] = tid * 16 + it;
    }

    {
        const int e = wave;
        float s = 0.f;
        #pragma unroll
        for (int ch = 0; ch < 8; ++ch) s += mgl[ch * 64 + lane][e];
        #pragma unroll
        for (int off = 32; off > 0; off >>= 1) s += __shfl_xor(s, off, 64);
        if (lane == 0) tot_s[e] = s;
    }
    __syncthreads();
    if (tid == 0) {
        float s = 0.f;
        #pragma unroll
        for (int e = 0; e < NE; ++e) {
            float m = tot_s[e] * (8.0f / 8192.0f);
            s += m * m;
        }
        out[(size_t)NTOK * DOUT] = s * 0.125f;
    }
}

// ---------------------------------------------------------------------------
// grouped GEMM v5: LDS-free, 1 wave (64 thr) per block, 64x64 output tile.
// Fragments loaded straight from global (A = per-lane token gather), cvt to
// bf16 in reg, 16x mfma_f32_16x16x32_bf16 per K-step (BK=32), 2-stage
// register double-buffer -> 16 loads in flight across each MFMA phase.
// Grid 4096: d = mlo | n<<3 | e<<7 | mhi<<10; m = mlo + 8*mhi (cap 2048 rows
// per expert). n-siblings of (m,e) are consecutive AND same-XCD (d%8=mlo).
// ---------------------------------------------------------------------------
__global__ __launch_bounds__(64) void moe_gemm(
    const float* __restrict__ x, const float* __restrict__ We,
    const float* __restrict__ be, const int* __restrict__ counts,
    const int* __restrict__ tok_list, float* __restrict__ out)
{
    const int d   = blockIdx.x;
    const int mlo = d & 7;
    const int n   = (d >> 3) & 15;
    const int e   = (d >> 7) & 7;
    const int mhi = d >> 10;
    const int cnt = counts[e];
    const int m0  = (mlo + 8 * mhi) * 64;
    if (m0 >= cnt) return;
    const int n0  = n * 64;

    const int lane = threadIdx.x;
    const int lrow = lane & 15;
    const int quad = lane >> 4;

    // tokens for the A-fragment rows this lane reads (rows m0 + i*16 + lrow)
    int atok[4];
    #pragma unroll
    for (int i = 0; i < 4; ++i) {
        int gr = m0 + i * 16 + lrow;
        atok[i] = tok_list[e * NTOK + (gr < cnt ? gr : cnt - 1)];
    }

    const float* aP[4];
    const float* bP[4];
    #pragma unroll
    for (int i = 0; i < 4; ++i)
        aP[i] = x + (size_t)atok[i] * DIN + quad * 8;
    #pragma unroll
    for (int j = 0; j < 4; ++j)
        bP[j] = We + ((size_t)e << 20) + ((size_t)(n0 + j * 16 + lrow) << 10) + quad * 8;

    f32x4 acc[4][4];
    #pragma unroll
    for (int i = 0; i < 4; ++i)
        #pragma unroll
        for (int j = 0; j < 4; ++j) acc[i][j] = (f32x4){0.f, 0.f, 0.f, 0.f};

    // two register stages (named, all indices compile-time -> no scratch)
    f32x4 A0[8], B0[8], A1[8], B1[8];

    #define LD(Ab, Bb, k0)                                       \
        do {                                                     \
            _Pragma("unroll")                                    \
            for (int i = 0; i < 4; ++i) {                        \
                Ab[2*i]   = *(const f32x4*)(aP[i] + (k0));       \
                Ab[2*i+1] = *(const f32x4*)(aP[i] + (k0) + 4);   \
                Bb[2*i]   = *(const f32x4*)(bP[i] + (k0));       \
                Bb[2*i+1] = *(const f32x4*)(bP[i] + (k0) + 4);   \
            }                                                    \
        } while (0)

    #define CP(Ab, Bb)                                                        \
        do {                                                                  \
            bf16x8 af[4], bf[4];                                              \
            _Pragma("unroll")                                                 \
            for (int i = 0; i < 4; ++i) {                                     \
                union { u16 h[8]; bf16x8 v; } ua, ub;                         \
                _Pragma("unroll")                                             \
                for (int q = 0; q < 4; ++q) {                                 \
                    ua.h[q]     = f2bf(Ab[2*i][q]);                           \
                    ua.h[4 + q] = f2bf(Ab[2*i+1][q]);                         \
                    ub.h[q]     = f2bf(Bb[2*i][q]);                           \
                    ub.h[4 + q] = f2bf(Bb[2*i+1][q]);                         \
                }                                                             \
                af[i] = ua.v; bf[i] = ub.v;                                   \
            }                                                                 \
            _Pragma("unroll")                                                 \
            for (int i = 0; i < 4; ++i)                                       \
                _Pragma("unroll")                                             \
                for (int j = 0; j < 4; ++j)                                   \
                    acc[i][j] = __builtin_amdgcn_mfma_f32_16x16x32_bf16(      \
                        af[i], bf[j], acc[i][j], 0, 0, 0);                    \
        } while (0)

    LD(A0, B0, 0);
    #pragma unroll 1
    for (int k0 = 0; k0 <= DIN - 128; k0 += 64) {
        LD(A1, B1, k0 + 32);   // in flight across CP(A0,B0)
        CP(A0, B0);
        LD(A0, B0, k0 + 64);   // in flight across CP(A1,B1)
        CP(A1, B1);
    }
    LD(A1, B1, DIN - 32);      // k=992
    CP(A0, B0);                // k=960
    CP(A1, B1);                // k=992

    #undef LD
    #undef CP

    // epilogue: D lane map col=lane&15 (N), row=quad*4+r (M); fp32 stores.
    // token for output row i*16+quad*4+r comes from lane (quad*4+r)'s atok[i].
    #pragma unroll
    for (int j = 0; j < 4; ++j) {
        const int col = n0 + j * 16 + lrow;
        const float bev = be[e * DOUT + col];
        #pragma unroll
        for (int i = 0; i < 4; ++i) {
            #pragma unroll
            for (int r = 0; r < 4; ++r) {
                const int rl = m0 + i * 16 + quad * 4 + r;
                const int tok = __shfl(atok[i], quad * 4 + r, 64);
                if (rl < cnt)
                    out[((size_t)tok << 10) + col] = acc[i][j][r] + bev;
            }
        }
    }
}

extern "C" void kernel_launch(void* const* d_in, const int* in_sizes, int n_in,
                              void* d_out, int out_size, void* d_ws, size_t ws_size,
                              hipStream_t stream) {
    const float* x  = (const float*)d_in[0];
    const float* We = (const float*)d_in[1];
    const float* be = (const float*)d_in[2];
    const float* Wg = (const float*)d_in[3];
    const float* bg = (const float*)d_in[4];
    float* out = (float*)d_out;

    int* counts   = (int*)d_ws;
    int* tok_list = (int*)((char*)d_ws + 256);
    u32* stage    = (u32*)((char*)d_ws + 256);

    gate_kernel<<<512, 256, 0, stream>>>(x, Wg, bg, stage);
    route_kernel<<<1, 512, 0, stream>>>(stage, counts, tok_list, out);
    moe_gemm<<<4096, 64, 0, stream>>>(x, We, be, counts, tok_list, out);
}

// Round 5
// 201.487 us; speedup vs baseline: 1.4114x; 1.4114x over previous
//
#include <hip/hip_runtime.h>
#include <hip/hip_bf16.h>

// SwitchLinear: B=4,S=2048,D_IN=1024,D_OUT=1024,E=8
// Established contract: ALL inputs fp32, OUTPUT fp32 (out_size=8388609 floats:
// 8192x1024 dense out + aux scalar). ws >= 262400 B. Routing = argmax of fp32
// gate logits; out[t,:] = x[t]@We[top1]^T + be[top1]; aux = mean((mean_gate*E)^2).
// Value GEMM: bf16 MFMA (input-rounding error ~1e-3 << 6.4e-2 threshold).
//
// v6: gemm = v3 structure (128x128 tile, BK=32, 4 waves, dim3(8,64,8) grid --
// the best-measured locality) with the K-loop rebuilt on the T3-minimum
// template: fp32 tiles staged via global_load_lds (16B DMA, no register
// round-trip, no staging VALU), double-buffered LDS (2x32KB, 2 blk/CU),
// ONE raw s_barrier + vmcnt(0) per K-step (prefetch covered by compute),
// fp32->bf16 cvt AFTER ds_read. Chunk-XOR swizzle (c ^= row&7) applied to
// the per-lane GLOBAL source (DMA dest must stay linear) and to the read
// side -> both at the 8-pass b128 bank floor.
// v3 (kept): zero-atomic routing via per-block records + 1-block scan kernel.
// Timing model: total ~= kernels + ~85us fixed harness overhead.

#define NTOK 8192
#define DIN  1024
#define DOUT 1024
#define NE   8

typedef unsigned short u16;
typedef unsigned int   u32;
typedef unsigned long long u64;
typedef short  bf16x8 __attribute__((ext_vector_type(8)));
typedef float  f32x4  __attribute__((ext_vector_type(4)));

__device__ __forceinline__ u16 f2bf(float f) {
    __hip_bfloat16 h = __float2bfloat16(f);   // RNE
    return *(u16*)&h;
}

// 16B global->LDS DMA (gfx950). LDS dest is wave-uniform base + lane*16.
#define GLDS16(g, l)                                                  \
    __builtin_amdgcn_global_load_lds(                                 \
        (__attribute__((address_space(1))) void*)(g),                 \
        (__attribute__((address_space(3))) void*)(l), 16, 0, 0)

// ws layout: [0,32) counts[8] | [256, 262400) tok_list[8][8192]
// First 32KB of tok_list region doubles as gate-record staging (512 x 64B).

// ---------------------------------------------------------------------------
// gate: 512 blocks x 256 thr; each block 16 tokens, each wave 4 tokens.
// Per token: 8 lane-groups x 8 lanes; group g computes expert g. No atomics.
// ---------------------------------------------------------------------------
__global__ __launch_bounds__(256) void gate_kernel(
    const float* __restrict__ x, const float* __restrict__ Wg,
    const float* __restrict__ bg, u32* __restrict__ stage)
{
    __shared__ int   am_s[16];
    __shared__ float mg_s[4][NE];

    const int tid  = threadIdx.x;
    const int wave = tid >> 6;
    const int lane = tid & 63;
    const int g    = lane >> 3;
    const int sub  = lane & 7;

    const float* wr = Wg + g * DIN + 4 * sub;

    float bgl[NE];
    #pragma unroll
    for (int e = 0; e < NE; ++e) bgl[e] = bg[e];

    float mgacc = 0.f;

    #pragma unroll 1
    for (int it = 0; it < 4; ++it) {
        const int t = blockIdx.x * 16 + wave * 4 + it;
        const float* xr = x + (size_t)t * DIN + 4 * sub;

        float acc0 = 0.f, acc1 = 0.f, acc2 = 0.f, acc3 = 0.f;
        #pragma unroll
        for (int j = 0; j < 8; ++j) {
            const int k = j * 128;
            f32x4 x0 = *(const f32x4*)(xr + k);
            f32x4 w0 = *(const f32x4*)(wr + k);
            f32x4 x1 = *(const f32x4*)(xr + k + 32);
            f32x4 w1 = *(const f32x4*)(wr + k + 32);
            f32x4 x2 = *(const f32x4*)(xr + k + 64);
            f32x4 w2 = *(const f32x4*)(wr + k + 64);
            f32x4 x3 = *(const f32x4*)(xr + k + 96);
            f32x4 w3 = *(const f32x4*)(wr + k + 96);
            #pragma unroll
            for (int q = 0; q < 4; ++q) {
                acc0 = fmaf(w0[q], x0[q], acc0);
                acc1 = fmaf(w1[q], x1[q], acc1);
                acc2 = fmaf(w2[q], x2[q], acc2);
                acc3 = fmaf(w3[q], x3[q], acc3);
            }
        }
        float acc = (acc0 + acc1) + (acc2 + acc3);

        acc += __shfl_xor(acc, 1, 64);
        acc += __shfl_xor(acc, 2, 64);
        acc += __shfl_xor(acc, 4, 64);

        float logit[NE];
        #pragma unroll
        for (int e = 0; e < NE; ++e)
            logit[e] = __shfl(acc, e * 8, 64) + bgl[e];

        float m = logit[0]; int am = 0;
        #pragma unroll
        for (int e = 1; e < NE; ++e) if (logit[e] > m) { m = logit[e]; am = e; }

        float p[NE], s = 0.f;
        #pragma unroll
        for (int e = 0; e < NE; ++e) { p[e] = __expf(logit[e] - m); s += p[e]; }
        const float inv = 1.f / s;

        float psel = p[0];
        #pragma unroll
        for (int e = 1; e < NE; ++e) psel = (lane == e) ? p[e] : psel;
        if (lane < NE) mgacc += psel * inv;

        if (lane == 0) am_s[wave * 4 + it] = am;
    }

    if (lane < NE) mg_s[wave][lane] = mgacc;
    __syncthreads();

    u32* rec = stage + (size_t)blockIdx.x * 16;
    if (tid == 0) {
        u64 pack = 0;
        #pragma unroll
        for (int i = 0; i < 16; ++i) pack |= (u64)am_s[i] << (4 * i);
        *(u64*)rec = pack;
    }
    if (tid < NE) {
        float s = mg_s[0][tid] + mg_s[1][tid] + mg_s[2][tid] + mg_s[3][tid];
        rec[2 + tid] = __float_as_uint(s);
    }
}

// ---------------------------------------------------------------------------
// route: 1 block x 512 threads. Thread i owns gate-block i (16 tokens).
// Count -> per-expert exclusive scan over blocks -> scatter -> counts/aux.
// ---------------------------------------------------------------------------
__global__ __launch_bounds__(512) void route_kernel(
    const u32* __restrict__ stage, int* __restrict__ counts,
    int* __restrict__ tok_list, float* __restrict__ out)
{
    __shared__ float mgl[512][NE];
    __shared__ int   c[512][9];
    __shared__ float tot_s[NE];

    const int tid  = threadIdx.x;
    const int wave = tid >> 6;
    const int lane = tid & 63;

    const u64 pack = *(const u64*)(stage + (size_t)tid * 16);
    #pragma unroll
    for (int e = 0; e < NE; ++e)
        mgl[tid][e] = __uint_as_float(stage[tid * 16 + 2 + e]);

    #pragma unroll
    for (int e = 0; e < 9; ++e) c[tid][e] = 0;

    #pragma unroll
    for (int it = 0; it < 16; ++it) {
        int e3 = (int)((pack >> (4 * it)) & 7);
        c[tid][e3]++;
    }
    __syncthreads();

    {
        const int e = wave;
        int carry = 0;
        #pragma unroll 1
        for (int ch = 0; ch < 8; ++ch) {
            int v = c[ch * 64 + lane][e];
            int incl = v;
            #pragma unroll
            for (int off = 1; off < 64; off <<= 1) {
                int n = __shfl_up(incl, off, 64);
                if (lane >= off) incl += n;
            }
            c[ch * 64 + lane][e] = incl - v + carry;
            carry += __shfl(incl, 63, 64);
        }
        if (lane == 0) counts[e] = carry;
    }
    __syncthreads();

    #pragma unroll
    for (int it = 0; it < 16; ++it) {
        int e3 = (int)((pack >> (4 * it)) & 7);
        int pos = c[tid][e3]++;
        tok_list[e3 * NTOK + pos] = tid * 16 + it;
    }

    {
        const int e = wave;
        float s = 0.f;
        #pragma unroll
        for (int ch = 0; ch < 8; ++ch) s += mgl[ch * 64 + lane][e];
        #pragma unroll
        for (int off = 32; off > 0; off >>= 1) s += __shfl_xor(s, off, 64);
        if (lane == 0) tot_s[e] = s;
    }
    __syncthreads();
    if (tid == 0) {
        float s = 0.f;
        #pragma unroll
        for (int e = 0; e < NE; ++e) {
            float m = tot_s[e] * (8.0f / 8192.0f);
            s += m * m;
        }
        out[(size_t)NTOK * DOUT] = s * 0.125f;
    }
}

// ---------------------------------------------------------------------------
// grouped GEMM v6: 128x128 tile, BK=32, 4 waves each 64x64.
// fp32 A/B tiles [128 rows][8 chunks of 4 floats] DMA'd to LDS via
// global_load_lds(16B): wave w covers rows [w*32,w*32+32), 4 instrs x 8 rows
// per matrix. Source chunk pre-swizzled (c ^ row&7) so the swizzled READ
// (chunk (2q+d)^(lrow&7)) is bank-floor. cvt to bf16 after ds_read.
// T3-minimum schedule: STAGE(next) / COMPUTE(cur) / vmcnt(0)+s_barrier.
// ---------------------------------------------------------------------------
__global__ __launch_bounds__(256) void moe_gemm(
    const float* __restrict__ x, const float* __restrict__ We,
    const float* __restrict__ be, const int* __restrict__ counts,
    const int* __restrict__ tok_list, float* __restrict__ out)
{
    const int e   = blockIdx.z;
    const int cnt = counts[e];
    const int m0  = blockIdx.y * 128;
    if (m0 >= cnt) return;
    const int n0  = blockIdx.x * 128;

    __shared__ float sA[2][128 * 32];   // 2 x 16 KB
    __shared__ float sB[2][128 * 32];   // 2 x 16 KB
    __shared__ int toks[128];

    const int tid = threadIdx.x;
    if (tid < 128) {
        int gr = m0 + tid;
        toks[tid] = (gr < cnt) ? tok_list[e * NTOK + gr] : tok_list[e * NTOK];
    }
    __syncthreads();

    const int lane = tid & 63;
    const int wave = tid >> 6;
    const int wm   = (wave & 1) * 64;
    const int wn   = (wave >> 1) * 64;
    const int lrow = lane & 15;
    const int quad = lane >> 4;
    const int l7   = lrow & 7;

    // DMA staging geometry: per instr, lane -> (row_off = lane>>3, chunk = lane&7)
    // LDS[r][c] = G[r][c ^ (r&7)]  (inverse swizzle on the global source)
    const int ro  = lane >> 3;
    const int csw = (lane & 7) ^ ro;

    const float* aSrc[4];
    const float* bSrc[4];
    #pragma unroll
    for (int i = 0; i < 4; ++i) {
        const int r = wave * 32 + i * 8 + ro;
        aSrc[i] = x + (size_t)toks[r] * DIN + csw * 4;
        bSrc[i] = We + ((size_t)e << 20) + ((size_t)(n0 + r) << 10) + csw * 4;
    }

    f32x4 acc[4][4];
    #pragma unroll
    for (int i = 0; i < 4; ++i)
        #pragma unroll
        for (int j = 0; j < 4; ++j) acc[i][j] = (f32x4){0.f, 0.f, 0.f, 0.f};

    #define STAGE(buf, k0)                                               \
        do {                                                             \
            _Pragma("unroll")                                            \
            for (int i = 0; i < 4; ++i) {                                \
                GLDS16(aSrc[i] + (k0), &sA[buf][(wave * 32 + i * 8) * 32]); \
                GLDS16(bSrc[i] + (k0), &sB[buf][(wave * 32 + i * 8) * 32]); \
            }                                                            \
        } while (0)

    // read chunks (2q)^l7, (2q+1)^l7 of row -> G chunks 2q, 2q+1 = k 8q..8q+7
    #define COMPUTE(buf)                                                      \
        do {                                                                  \
            bf16x8 af[4], bv[4];                                              \
            _Pragma("unroll")                                                 \
            for (int i = 0; i < 4; ++i) {                                     \
                const int ra = (wm + i * 16 + lrow) * 32;                     \
                const int rb = (wn + i * 16 + lrow) * 32;                     \
                f32x4 a0 = *(const f32x4*)&sA[buf][ra + (((2*quad)  ^l7)<<2)];\
                f32x4 a1 = *(const f32x4*)&sA[buf][ra + (((2*quad+1)^l7)<<2)];\
                f32x4 b0 = *(const f32x4*)&sB[buf][rb + (((2*quad)  ^l7)<<2)];\
                f32x4 b1 = *(const f32x4*)&sB[buf][rb + (((2*quad+1)^l7)<<2)];\
                union { u16 h[8]; bf16x8 v; } ua, ub;                         \
                _Pragma("unroll")                                             \
                for (int q = 0; q < 4; ++q) {                                 \
                    ua.h[q]     = f2bf(a0[q]);                                \
                    ua.h[4 + q] = f2bf(a1[q]);                                \
                    ub.h[q]     = f2bf(b0[q]);                                \
                    ub.h[4 + q] = f2bf(b1[q]);                                \
                }                                                             \
                af[i] = ua.v; bv[i] = ub.v;                                   \
            }                                                                 \
            _Pragma("unroll")                                                 \
            for (int i = 0; i < 4; ++i)                                       \
                _Pragma("unroll")                                             \
                for (int j = 0; j < 4; ++j)                                   \
                    acc[i][j] = __builtin_amdgcn_mfma_f32_16x16x32_bf16(      \
                        af[i], bv[j], acc[i][j], 0, 0, 0);                    \
        } while (0)

    // prologue: tile 0 -> buf 0, drain, barrier
    STAGE(0, 0);
    asm volatile("s_waitcnt vmcnt(0)" ::: "memory");
    __builtin_amdgcn_s_barrier();

    int buf = 0;
    #pragma unroll 1
    for (int k0 = 0; k0 < DIN; k0 += 32) {
        if (k0 + 32 < DIN) STAGE(buf ^ 1, k0 + 32);  // prefetch next tile
        COMPUTE(buf);                                 // covers DMA latency
        asm volatile("s_waitcnt vmcnt(0)" ::: "memory");
        __builtin_amdgcn_s_barrier();                 // one barrier per K-step
        buf ^= 1;
    }

    #undef STAGE
    #undef COMPUTE

    // epilogue: D lane map col=lane&15 (N), row=quad*4+r (M); fp32 stores
    #pragma unroll
    for (int j = 0; j < 4; ++j) {
        const int col = n0 + wn + j * 16 + lrow;
        const float bev = be[e * DOUT + col];
        #pragma unroll
        for (int i = 0; i < 4; ++i) {
            #pragma unroll
            for (int r = 0; r < 4; ++r) {
                const int rl = wm + i * 16 + quad * 4 + r;
                if (m0 + rl < cnt) {
                    const int tok = toks[rl];
                    out[((size_t)tok << 10) + col] = acc[i][j][r] + bev;
                }
            }
        }
    }
}

extern "C" void kernel_launch(void* const* d_in, const int* in_sizes, int n_in,
                              void* d_out, int out_size, void* d_ws, size_t ws_size,
                              hipStream_t stream) {
    const float* x  = (const float*)d_in[0];
    const float* We = (const float*)d_in[1];
    const float* be = (const float*)d_in[2];
    const float* Wg = (const float*)d_in[3];
    const float* bg = (const float*)d_in[4];
    float* out = (float*)d_out;

    int* counts   = (int*)d_ws;
    int* tok_list = (int*)((char*)d_ws + 256);
    u32* stage    = (u32*)((char*)d_ws + 256);

    gate_kernel<<<512, 256, 0, stream>>>(x, Wg, bg, stage);
    route_kernel<<<1, 512, 0, stream>>>(stage, counts, tok_list, out);
    moe_gemm<<<dim3(8, 64, 8), 256, 0, stream>>>(x, We, be, counts, tok_list, out);
}

// Round 6
// 181.957 us; speedup vs baseline: 1.5629x; 1.1073x over previous
//
#include <hip/hip_runtime.h>
#include <hip/hip_bf16.h>

// SwitchLinear: B=4,S=2048,D_IN=1024,D_OUT=1024,E=8
// Established contract: ALL inputs fp32, OUTPUT fp32 (out_size=8388609 floats:
// 8192x1024 dense out + aux scalar). ws >= 262400 B. Routing = argmax of fp32
// gate logits; out[t,:] = x[t]@We[top1]^T + be[top1]; aux = mean((mean_gate*E)^2).
// Value GEMM: bf16 MFMA (input-rounding error ~1e-3 << 6.4e-2 threshold).
//
// v7: TLP-first gemm. Measured v3-v6: latency-serialization bound (MfmaUtil
// 7-9% always), only resident blocks hide the chain; BM=128 gave just 512
// active blocks (2/CU). Now BM=64,BN=128,BK=64 -> ~1088 active (4.25/CU),
// single-buffered bf16 LDS 24.3KB (6 blk/CU by LDS), 4 waves x (64x32).
// Staging/read = v4's HW-VERIFIED 0-conflict XOR pattern (chunk ^= row&7,
// 128B rows; v3/v6's 4.5M conflicts were the write side). Next-tile loads
// issue right after ds_write -> in flight across COMPUTE. Grid keeps v3's
// proven dim3(8,*,8) ordering (v4's 1-D remap thrashed L2: FETCH +60MB).
// v3 (kept): zero-atomic routing via per-block records + 1-block scan kernel.
// Timing model: total ~= kernels + ~85us fixed harness overhead.

#define NTOK 8192
#define DIN  1024
#define DOUT 1024
#define NE   8

typedef unsigned short u16;
typedef unsigned int   u32;
typedef unsigned long long u64;
typedef short  bf16x8 __attribute__((ext_vector_type(8)));
typedef float  f32x4  __attribute__((ext_vector_type(4)));

__device__ __forceinline__ u16 f2bf(float f) {
    __hip_bfloat16 h = __float2bfloat16(f);   // RNE
    return *(u16*)&h;
}

// ws layout: [0,32) counts[8] | [256, 262400) tok_list[8][8192]
// First 32KB of tok_list region doubles as gate-record staging (512 x 64B).

// ---------------------------------------------------------------------------
// gate: 512 blocks x 256 thr; each block 16 tokens, each wave 4 tokens.
// Per token: 8 lane-groups x 8 lanes; group g computes expert g. No atomics.
// ---------------------------------------------------------------------------
__global__ __launch_bounds__(256) void gate_kernel(
    const float* __restrict__ x, const float* __restrict__ Wg,
    const float* __restrict__ bg, u32* __restrict__ stage)
{
    __shared__ int   am_s[16];
    __shared__ float mg_s[4][NE];

    const int tid  = threadIdx.x;
    const int wave = tid >> 6;
    const int lane = tid & 63;
    const int g    = lane >> 3;
    const int sub  = lane & 7;

    const float* wr = Wg + g * DIN + 4 * sub;

    float bgl[NE];
    #pragma unroll
    for (int e = 0; e < NE; ++e) bgl[e] = bg[e];

    float mgacc = 0.f;

    #pragma unroll 1
    for (int it = 0; it < 4; ++it) {
        const int t = blockIdx.x * 16 + wave * 4 + it;
        const float* xr = x + (size_t)t * DIN + 4 * sub;

        float acc0 = 0.f, acc1 = 0.f, acc2 = 0.f, acc3 = 0.f;
        #pragma unroll
        for (int j = 0; j < 8; ++j) {
            const int k = j * 128;
            f32x4 x0 = *(const f32x4*)(xr + k);
            f32x4 w0 = *(const f32x4*)(wr + k);
            f32x4 x1 = *(const f32x4*)(xr + k + 32);
            f32x4 w1 = *(const f32x4*)(wr + k + 32);
            f32x4 x2 = *(const f32x4*)(xr + k + 64);
            f32x4 w2 = *(const f32x4*)(wr + k + 64);
            f32x4 x3 = *(const f32x4*)(xr + k + 96);
            f32x4 w3 = *(const f32x4*)(wr + k + 96);
            #pragma unroll
            for (int q = 0; q < 4; ++q) {
                acc0 = fmaf(w0[q], x0[q], acc0);
                acc1 = fmaf(w1[q], x1[q], acc1);
                acc2 = fmaf(w2[q], x2[q], acc2);
                acc3 = fmaf(w3[q], x3[q], acc3);
            }
        }
        float acc = (acc0 + acc1) + (acc2 + acc3);

        acc += __shfl_xor(acc, 1, 64);
        acc += __shfl_xor(acc, 2, 64);
        acc += __shfl_xor(acc, 4, 64);

        float logit[NE];
        #pragma unroll
        for (int e = 0; e < NE; ++e)
            logit[e] = __shfl(acc, e * 8, 64) + bgl[e];

        float m = logit[0]; int am = 0;
        #pragma unroll
        for (int e = 1; e < NE; ++e) if (logit[e] > m) { m = logit[e]; am = e; }

        float p[NE], s = 0.f;
        #pragma unroll
        for (int e = 0; e < NE; ++e) { p[e] = __expf(logit[e] - m); s += p[e]; }
        const float inv = 1.f / s;

        float psel = p[0];
        #pragma unroll
        for (int e = 1; e < NE; ++e) psel = (lane == e) ? p[e] : psel;
        if (lane < NE) mgacc += psel * inv;

        if (lane == 0) am_s[wave * 4 + it] = am;
    }

    if (lane < NE) mg_s[wave][lane] = mgacc;
    __syncthreads();

    u32* rec = stage + (size_t)blockIdx.x * 16;
    if (tid == 0) {
        u64 pack = 0;
        #pragma unroll
        for (int i = 0; i < 16; ++i) pack |= (u64)am_s[i] << (4 * i);
        *(u64*)rec = pack;
    }
    if (tid < NE) {
        float s = mg_s[0][tid] + mg_s[1][tid] + mg_s[2][tid] + mg_s[3][tid];
        rec[2 + tid] = __float_as_uint(s);
    }
}

// ---------------------------------------------------------------------------
// route: 1 block x 512 threads. Thread i owns gate-block i (16 tokens).
// Count -> per-expert exclusive scan over blocks -> scatter -> counts/aux.
// ---------------------------------------------------------------------------
__global__ __launch_bounds__(512) void route_kernel(
    const u32* __restrict__ stage, int* __restrict__ counts,
    int* __restrict__ tok_list, float* __restrict__ out)
{
    __shared__ float mgl[512][NE];
    __shared__ int   c[512][9];
    __shared__ float tot_s[NE];

    const int tid  = threadIdx.x;
    const int wave = tid >> 6;
    const int lane = tid & 63;

    const u64 pack = *(const u64*)(stage + (size_t)tid * 16);
    #pragma unroll
    for (int e = 0; e < NE; ++e)
        mgl[tid][e] = __uint_as_float(stage[tid * 16 + 2 + e]);

    #pragma unroll
    for (int e = 0; e < 9; ++e) c[tid][e] = 0;

    #pragma unroll
    for (int it = 0; it < 16; ++it) {
        int e3 = (int)((pack >> (4 * it)) & 7);
        c[tid][e3]++;
    }
    __syncthreads();

    {
        const int e = wave;
        int carry = 0;
        #pragma unroll 1
        for (int ch = 0; ch < 8; ++ch) {
            int v = c[ch * 64 + lane][e];
            int incl = v;
            #pragma unroll
            for (int off = 1; off < 64; off <<= 1) {
                int n = __shfl_up(incl, off, 64);
                if (lane >= off) incl += n;
            }
            c[ch * 64 + lane][e] = incl - v + carry;
            carry += __shfl(incl, 63, 64);
        }
        if (lane == 0) counts[e] = carry;
    }
    __syncthreads();

    #pragma unroll
    for (int it = 0; it < 16; ++it) {
        int e3 = (int)((pack >> (4 * it)) & 7);
        int pos = c[tid][e3]++;
        tok_list[e3 * NTOK + pos] = tid * 16 + it;
    }

    {
        const int e = wave;
        float s = 0.f;
        #pragma unroll
        for (int ch = 0; ch < 8; ++ch) s += mgl[ch * 64 + lane][e];
        #pragma unroll
        for (int off = 32; off > 0; off >>= 1) s += __shfl_xor(s, off, 64);
        if (lane == 0) tot_s[e] = s;
    }
    __syncthreads();
    if (tid == 0) {
        float s = 0.f;
        #pragma unroll
        for (int e = 0; e < NE; ++e) {
            float m = tot_s[e] * (8.0f / 8192.0f);
            s += m * m;
        }
        out[(size_t)NTOK * DOUT] = s * 0.125f;
    }
}

// ---------------------------------------------------------------------------
// grouped GEMM v7: 64x128 tile, BK=64, 4 waves each 64x32 (4x2 of 16x16x32).
// LDS: bf16 sA[64][64] (8KB) + sB[128][64] (16KB), single-buffered.
// Staging: fp32 global -> reg -> cvt -> ds_write at XOR-swizzled chunk
// (cx = ch ^ (row&7); rows 128B) -- v4-verified 0 bank conflicts, both sides.
// Schedule: barrier / write(k) / issue loads(k+1) / barrier / compute(k).
// Grid dim3(8 n, 128 m, 8 e): ~1088 active blocks = 4.25/CU.
// ---------------------------------------------------------------------------
__global__ __launch_bounds__(256) void moe_gemm(
    const float* __restrict__ x, const float* __restrict__ We,
    const float* __restrict__ be, const int* __restrict__ counts,
    const int* __restrict__ tok_list, float* __restrict__ out)
{
    const int e   = blockIdx.z;
    const int cnt = counts[e];
    const int m0  = blockIdx.y * 64;
    if (m0 >= cnt) return;
    const int n0  = blockIdx.x * 128;

    __shared__ u16 sA[64 * 64];    // 8 KB
    __shared__ u16 sB[128 * 64];   // 16 KB
    __shared__ int toks[64];

    const int tid = threadIdx.x;
    if (tid < 64) {
        int gr = m0 + tid;
        toks[tid] = (gr < cnt) ? tok_list[e * NTOK + gr] : tok_list[e * NTOK];
    }
    __syncthreads();

    const int lane = tid & 63;
    const int wave = tid >> 6;
    const int wn   = wave * 32;          // wave's N offset within tile
    const int lrow = lane & 15;
    const int quad = lane >> 4;
    const int l7   = lrow & 7;

    f32x4 acc[4][2];
    #pragma unroll
    for (int i = 0; i < 4; ++i)
        #pragma unroll
        for (int j = 0; j < 2; ++j) acc[i][j] = (f32x4){0.f, 0.f, 0.f, 0.f};

    // staging map: thread -> (srow = tid>>3 in 0..31, chunk ch = tid&7 of 8
    // floats). A covers rows srow, srow+32; B rows srow + 32*s, s=0..3.
    // Swizzled store chunk cx = ch ^ (srow&7)  (32*s keeps row&7 invariant).
    const int srow = tid >> 3;
    const int ch   = tid & 7;
    const int cx   = ch ^ (srow & 7);

    const float* aS[2];
    const float* bS[4];
    #pragma unroll
    for (int s = 0; s < 2; ++s)
        aS[s] = x + (size_t)toks[srow + 32 * s] * DIN + ch * 8;
    #pragma unroll
    for (int s = 0; s < 4; ++s)
        bS[s] = We + ((size_t)e << 20) + ((size_t)(n0 + srow + 32 * s) << 10) + ch * 8;

    f32x4 ar[2][2], br[4][2];    // [slot][half-chunk]

    #define LOADR(k0)                                            \
        do {                                                     \
            _Pragma("unroll")                                    \
            for (int s = 0; s < 2; ++s) {                        \
                ar[s][0] = *(const f32x4*)(aS[s] + (k0));        \
                ar[s][1] = *(const f32x4*)(aS[s] + (k0) + 4);    \
            }                                                    \
            _Pragma("unroll")                                    \
            for (int s = 0; s < 4; ++s) {                        \
                br[s][0] = *(const f32x4*)(bS[s] + (k0));        \
                br[s][1] = *(const f32x4*)(bS[s] + (k0) + 4);    \
            }                                                    \
        } while (0)

    #define STOREW()                                                     \
        do {                                                             \
            _Pragma("unroll")                                            \
            for (int s = 0; s < 2; ++s) {                                \
                union { u16 h[8]; uint4 u; } ua;                         \
                _Pragma("unroll")                                        \
                for (int q = 0; q < 4; ++q) {                            \
                    ua.h[q]     = f2bf(ar[s][0][q]);                     \
                    ua.h[4 + q] = f2bf(ar[s][1][q]);                     \
                }                                                        \
                *(uint4*)&sA[(srow + 32 * s) * 64 + cx * 8] = ua.u;      \
            }                                                            \
            _Pragma("unroll")                                            \
            for (int s = 0; s < 4; ++s) {                                \
                union { u16 h[8]; uint4 u; } ub;                         \
                _Pragma("unroll")                                        \
                for (int q = 0; q < 4; ++q) {                            \
                    ub.h[q]     = f2bf(br[s][0][q]);                     \
                    ub.h[4 + q] = f2bf(br[s][1][q]);                     \
                }                                                        \
                *(uint4*)&sB[(srow + 32 * s) * 64 + cx * 8] = ub.u;      \
            }                                                            \
        } while (0)

    // read chunk (ks*4+quad)^l7 of each fragment row (v4-verified pattern)
    #define COMPUTE()                                                         \
        do {                                                                  \
            bf16x8 af[2][4], bv[2][2];                                        \
            _Pragma("unroll")                                                 \
            for (int ks = 0; ks < 2; ++ks) {                                  \
                const int so = ((ks * 4 + quad) ^ l7) * 8;                    \
                _Pragma("unroll")                                             \
                for (int i = 0; i < 4; ++i)                                   \
                    af[ks][i] = *(const bf16x8*)&sA[(i * 16 + lrow) * 64 + so]; \
                _Pragma("unroll")                                             \
                for (int j = 0; j < 2; ++j)                                   \
                    bv[ks][j] = *(const bf16x8*)&sB[(wn + j * 16 + lrow) * 64 + so]; \
            }                                                                 \
            _Pragma("unroll")                                                 \
            for (int ks = 0; ks < 2; ++ks)                                    \
                _Pragma("unroll")                                             \
                for (int i = 0; i < 4; ++i)                                   \
                    _Pragma("unroll")                                         \
                    for (int j = 0; j < 2; ++j)                               \
                        acc[i][j] = __builtin_amdgcn_mfma_f32_16x16x32_bf16(  \
                            af[ks][i], bv[ks][j], acc[i][j], 0, 0, 0);        \
        } while (0)

    LOADR(0);
    #pragma unroll 1
    for (int k0 = 0; k0 < DIN; k0 += 64) {
        __syncthreads();                       // prior compute done reading
        STOREW();                              // cvt regs -> LDS
        if (k0 + 64 < DIN) LOADR(k0 + 64);     // next tile in flight over compute
        __syncthreads();                       // writes visible
        COMPUTE();
    }

    #undef LOADR
    #undef STOREW
    #undef COMPUTE

    // epilogue: D lane map col=lane&15 (N), row=quad*4+r (M); fp32 stores
    #pragma unroll
    for (int j = 0; j < 2; ++j) {
        const int col = n0 + wn + j * 16 + lrow;
        const float bev = be[e * DOUT + col];
        #pragma unroll
        for (int i = 0; i < 4; ++i) {
            #pragma unroll
            for (int r = 0; r < 4; ++r) {
                const int rl = i * 16 + quad * 4 + r;
                if (m0 + rl < cnt) {
                    const int tok = toks[rl];
                    out[((size_t)tok << 10) + col] = acc[i][j][r] + bev;
                }
            }
        }
    }
}

extern "C" void kernel_launch(void* const* d_in, const int* in_sizes, int n_in,
                              void* d_out, int out_size, void* d_ws, size_t ws_size,
                              hipStream_t stream) {
    const float* x  = (const float*)d_in[0];
    const float* We = (const float*)d_in[1];
    const float* be = (const float*)d_in[2];
    const float* Wg = (const float*)d_in[3];
    const float* bg = (const float*)d_in[4];
    float* out = (float*)d_out;

    int* counts   = (int*)d_ws;
    int* tok_list = (int*)((char*)d_ws + 256);
    u32* stage    = (u32*)((char*)d_ws + 256);

    gate_kernel<<<512, 256, 0, stream>>>(x, Wg, bg, stage);
    route_kernel<<<1, 512, 0, stream>>>(stage, counts, tok_list, out);
    moe_gemm<<<dim3(8, 128, 8), 256, 0, stream>>>(x, We, be, counts, tok_list, out);
}